// Round 7
// baseline (400.696 us; speedup 1.0000x reference)
//
#include <hip/hip_runtime.h>
#include <hip/hip_bf16.h>
#include <math.h>

// Problem constants
#define B 64
#define T 1000
#define RNN_DIM 1024
#define EMB_DIM 512
#define ATT_DIM 128
#define LOC_DIM 32
#define KSIZE 31
#define PAD 15          // SAME padding for K=31
#define ET 64           // t-positions per energy block (16 tiles, last partial)
#define ESL 32          // e-floats per context block slice (16 slices)

// ============================ R11: DIAGNOSTIC BUILD =========================
// Harness poison-fills (~76 us) crowd the top-5, hiding our kernels. This
// round: energy and softmax_context repeat their body 8x over ROTATED slices
// ((blockIdx.y+rep)&15) so every rep is HBM-cold, outputs written only at
// rep==0 (own slice), rep>0 results kept alive via asm. Both kernels become
// ~8x longer -> visible in top-5 with counters. True per-kernel time = dur/8.
// Next round reverts the rep loops and applies the fix where the time is.
#define REPS 8

typedef __attribute__((ext_vector_type(4))) float f32x4;
typedef __attribute__((ext_vector_type(8))) short bf16x8;

__device__ inline unsigned short bf16_rne(float x) {
    unsigned u = __float_as_uint(x);
    u += 0x7fff + ((u >> 16) & 1);          // round-to-nearest-even
    return (unsigned short)(u >> 16);
}

// ---------------------------------------------------------------------------
// Kernel 1: pq[b][a] = dot(hidden[b, :1024], Wq[a, :1024])  (unchanged)
// ---------------------------------------------------------------------------
__global__ __launch_bounds__(256) void pq_kernel(
    const float* __restrict__ hidden,   // (B, 1024)
    const float* __restrict__ Wq,       // (128, 1024)
    float* __restrict__ pq)             // (B, 128)
{
    int gwave = (blockIdx.x * blockDim.x + threadIdx.x) >> 6;
    int lane  = threadIdx.x & 63;
    int b = gwave >> 7;     // / 128
    int a = gwave & 127;

    const float4* h4 = (const float4*)(hidden + (size_t)b * RNN_DIM);
    const float4* w4 = (const float4*)(Wq + (size_t)a * RNN_DIM);

    float acc = 0.f;
#pragma unroll
    for (int j = 0; j < 4; ++j) {
        float4 h = h4[j * 64 + lane];
        float4 w = w4[j * 64 + lane];
        acc += h.x * w.x + h.y * w.y + h.z * w.z + h.w * w.w;
    }
#pragma unroll
    for (int off = 32; off > 0; off >>= 1)
        acc += __shfl_down(acc, off, 64);
    if (lane == 0) pq[gwave] = acc;
}

// ---------------------------------------------------------------------------
// Kernel 2 (R6 structure + x8 rotated-slice diagnostic loop).
// ---------------------------------------------------------------------------
__global__ __launch_bounds__(256) void energy_kernel(
    const float* __restrict__ aw,       // (B, 2, T)
    const float* __restrict__ cw,       // (32, 2, 31)
    const float* __restrict__ wl,       // (128, 32)
    const float* __restrict__ pq,       // (B, 128)
    const float* __restrict__ pm,       // (B, T, 128)
    const float* __restrict__ v,        // (128)
    float* __restrict__ energy)         // (B, T)
{
    __shared__ float aw_lds[2][ET + 2 * PAD];     // [2][94]
    __shared__ float cw_lds[LOC_DIM][2][KSIZE];   // 2-way, free
    __shared__ __align__(16) unsigned short wl_hi[ATT_DIM][LOC_DIM];  // bf16
    __shared__ __align__(16) unsigned short wl_lo[ATT_DIM][LOC_DIM];  // bf16
    __shared__ __align__(16) unsigned short loc_hi[ET][LOC_DIM];      // bf16
    __shared__ __align__(16) unsigned short loc_lo[ET][LOC_DIM];      // bf16
    __shared__ float pq_lds[ATT_DIM];
    __shared__ float v_lds[ATT_DIM];

    const int b   = blockIdx.x;
    const int tid = threadIdx.x;

    const int w   = tid >> 6;     // wave 0..3: owns t rows [16w, 16w+16)
    const int l   = tid & 63;
    const int c15 = l & 15;       // A-row / B-col / C-col within tile
    const int g   = l >> 4;       // k-group (frags), C row-group

#pragma unroll 1
    for (int rep = 0; rep < REPS; ++rep) {
        const int t0 = ((blockIdx.y + rep) & 15) * ET;   // rotated slice

        // ---- stage small weights (cw/wl/pq/v rep-invariant; aw tile moves) ----
        for (int i = tid; i < LOC_DIM * 2 * KSIZE; i += 256)
            ((float*)cw_lds)[i] = cw[i];
        for (int i = tid; i < ATT_DIM * LOC_DIM; i += 256) {
            float x = wl[i];
            unsigned short h = bf16_rne(x);
            float hf = __uint_as_float((unsigned)h << 16);
            wl_hi[i >> 5][i & 31] = h;
            wl_lo[i >> 5][i & 31] = bf16_rne(x - hf);
        }
        if (tid < ATT_DIM) {
            pq_lds[tid] = pq[b * ATT_DIM + tid];
            v_lds[tid]  = v[tid];
        }
        for (int i = tid; i < 2 * (ET + 2 * PAD); i += 256) {
            int ch = i / (ET + 2 * PAD);
            int p  = i % (ET + 2 * PAD);
            int t  = t0 + p - PAD;
            aw_lds[ch][p] = (t >= 0 && t < T) ? aw[(size_t)b * 2 * T + ch * T + t] : 0.f;
        }
        __syncthreads();

        // ---- Phase 1: conv. thread = (c = tid&31, tg = tid>>5), 8 t's each ----
        {
            const int c  = tid & 31;
            const int tg = tid >> 5;
            float cacc[8];
#pragma unroll
            for (int j = 0; j < 8; ++j) cacc[j] = 0.f;
#pragma unroll
            for (int ch = 0; ch < 2; ++ch) {
                float awr[KSIZE + 7];   // 38-float sliding window in registers
#pragma unroll
                for (int j = 0; j < KSIZE + 7; ++j) awr[j] = aw_lds[ch][tg * 8 + j];
#pragma unroll
                for (int k = 0; k < KSIZE; ++k) {
                    float cv = cw_lds[c][ch][k];   // 2-way broadcast, free
#pragma unroll
                    for (int j = 0; j < 8; ++j) cacc[j] += cv * awr[k + j];
                }
            }
#pragma unroll
            for (int j = 0; j < 8; ++j) {
                float x = cacc[j];
                unsigned short h = bf16_rne(x);
                float hf = __uint_as_float((unsigned)h << 16);
                loc_hi[tg * 8 + j][c] = h;
                loc_lo[tg * 8 + j][c] = bf16_rne(x - hf);
            }
        }

        // ---- pm -> MFMA C-in accumulator (R6 placement: after conv) ----
        f32x4 acc[8];
        {
            const float* pmb = pm + (size_t)b * T * ATT_DIM;
            const int tbase = t0 + 16 * w + 4 * g;
#pragma unroll
            for (int n = 0; n < 8; ++n) {
#pragma unroll
                for (int r = 0; r < 4; ++r) {
                    int t = tbase + r;
                    acc[n][r] = (t < T) ? pmb[(size_t)t * ATT_DIM + 16 * n + c15] : 0.f;
                }
            }
        }
        __syncthreads();

        // ---- Phase 2: E(64x128) = loc(64x32) x wl^T via MFMA, split-bf16 ----
        {
            bf16x8 aH = *(const bf16x8*)&loc_hi[16 * w + c15][8 * g];
            bf16x8 aL = *(const bf16x8*)&loc_lo[16 * w + c15][8 * g];
#pragma unroll
            for (int n = 0; n < 8; ++n) {
                bf16x8 bH = *(const bf16x8*)&wl_hi[16 * n + c15][8 * g];
                bf16x8 bL = *(const bf16x8*)&wl_lo[16 * n + c15][8 * g];
                acc[n] = __builtin_amdgcn_mfma_f32_16x16x32_bf16(aH, bH, acc[n], 0, 0, 0);
                acc[n] = __builtin_amdgcn_mfma_f32_16x16x32_bf16(aH, bL, acc[n], 0, 0, 0);
                acc[n] = __builtin_amdgcn_mfma_f32_16x16x32_bf16(aL, bH, acc[n], 0, 0, 0);
            }
        }

        // ---- epilogue: e = acc + pq; tanh; v-dot; reduce over 16-lane group ----
        {
            float s[4] = {0.f, 0.f, 0.f, 0.f};
#pragma unroll
            for (int n = 0; n < 8; ++n) {
                const float pqa = pq_lds[16 * n + c15];
                const float va  = v_lds[16 * n + c15];
#pragma unroll
                for (int r = 0; r < 4; ++r) {
                    float e = acc[n][r] + pqa;
                    float ex = __expf(2.f * e);
                    float th = 1.f - 2.f * __builtin_amdgcn_rcpf(1.f + ex);
                    s[r] += va * th;
                }
            }
#pragma unroll
            for (int r = 0; r < 4; ++r) {
                s[r] += __shfl_xor(s[r], 1, 64);
                s[r] += __shfl_xor(s[r], 2, 64);
                s[r] += __shfl_xor(s[r], 4, 64);
                s[r] += __shfl_xor(s[r], 8, 64);
            }
            // keep rep>0 results alive (prevents DCE of the whole rep body)
            asm volatile("" :: "v"(s[0]), "v"(s[1]), "v"(s[2]), "v"(s[3]));
            if (rep == 0 && c15 == 0) {
                const int tbase = t0 + 16 * w + 4 * g;
#pragma unroll
                for (int r = 0; r < 4; ++r) {
                    int t = tbase + r;
                    if (t < T) energy[b * T + t] = s[r];
                }
            }
        }
        __syncthreads();   // protect LDS before next rep's staging
    }
}

// ---------------------------------------------------------------------------
// Kernel 3 (R4 structure + x8 rotated-slice diagnostic loop).
// ---------------------------------------------------------------------------
__global__ __launch_bounds__(256) void softmax_context_kernel(
    const float* __restrict__ memory,        // (B, T, 512)
    const float* __restrict__ energy,        // (B, T) in ws
    const unsigned char* __restrict__ mask,  // (B, T) bool
    float* __restrict__ out)                 // [B*512 ctx][B*1000 weights]
{
    __shared__ float w_lds[1024];            // normalized weights, pad = 0
    __shared__ float sred[4];
    __shared__ float cred[4][ESL];

    const int b   = blockIdx.x;
    const int tid = threadIdx.x;
    const int col = tid & 7;            // float4 index within 32-float slice
    const int rg  = tid >> 3;           // 0..31 row-group

#pragma unroll 1
    for (int rep = 0; rep < REPS; ++rep) {
        const int e0 = (((int)blockIdx.y + rep) & 15) * ESL;   // rotated slice

        // ---- (1) energy + mask loads (rep-invariant, L2) ----
        float e[4];
#pragma unroll
        for (int j = 0; j < 4; ++j) {
            int t = tid + j * 256;
            bool ok = (t < T);
            float val = ok ? energy[b * T + t] : -INFINITY;
            unsigned char m = ok ? mask[b * T + t] : (unsigned char)1;
            e[j] = (ok && !m) ? val : -INFINITY;
        }

        // ---- (2) prefetch context tile 0 at this rep's slice ----
        const float4* mem4 = (const float4*)(memory + (size_t)b * T * EMB_DIM + e0);
        float4 mA[8], mB[8];
#pragma unroll
        for (int u = 0; u < 8; ++u)
            mA[u] = mem4[(size_t)(rg + 32 * u) * 128 + col];

        // ---- (3) softmax while tile-0 HBM loads fly ----
        float mx = fmaxf(fmaxf(e[0], e[1]), fmaxf(e[2], e[3]));
#pragma unroll
        for (int off = 32; off > 0; off >>= 1)
            mx = fmaxf(mx, __shfl_down(mx, off, 64));
        if ((tid & 63) == 0) sred[tid >> 6] = mx;
        __syncthreads();
        mx = fmaxf(fmaxf(sred[0], sred[1]), fmaxf(sred[2], sred[3]));
        __syncthreads();

        float sum = 0.f;
        float ex[4];
#pragma unroll
        for (int j = 0; j < 4; ++j) {
            ex[j] = (e[j] == -INFINITY) ? 0.f : __expf(e[j] - mx);
            sum += ex[j];
        }
#pragma unroll
        for (int off = 32; off > 0; off >>= 1)
            sum += __shfl_down(sum, off, 64);
        if ((tid & 63) == 0) sred[tid >> 6] = sum;
        __syncthreads();
        sum = sred[0] + sred[1] + sred[2] + sred[3];
        float inv = 1.f / sum;

#pragma unroll
        for (int j = 0; j < 4; ++j) {
            int t = tid + j * 256;
            float wv = ex[j] * inv;
            w_lds[t] = (t < T) ? wv : 0.f;           // pads 1000..1023 = 0
            if (rep == 0 && blockIdx.y == 0 && t < T)
                out[B * EMB_DIM + b * T + t] = wv;   // weights output (rep 0 only)
        }
        __syncthreads();   // w_lds ready

        // ---- (4) pipelined context accumulation at this rep's slice ----
        float4 acc = {0.f, 0.f, 0.f, 0.f};

#define CTX_ISSUE(buf, base)                                              \
        _Pragma("unroll")                                                 \
        for (int u = 0; u < 8; ++u)                                       \
            buf[u] = mem4[(size_t)((base) + rg + 32 * u) * 128 + col];

#define CTX_ISSUE_CLAMP(buf, base)                                        \
        _Pragma("unroll")                                                 \
        for (int u = 0; u < 8; ++u) {                                     \
            int r  = (base) + rg + 32 * u;                                \
            int rc = (r < T) ? r : (T - 1);                               \
            buf[u] = mem4[(size_t)rc * 128 + col];                        \
        }

#define CTX_CONSUME(buf, base)                                            \
        _Pragma("unroll")                                                 \
        for (int u = 0; u < 8; ++u) {                                     \
            float wt = w_lds[(base) + rg + 32 * u];                       \
            acc.x += wt * buf[u].x; acc.y += wt * buf[u].y;               \
            acc.z += wt * buf[u].z; acc.w += wt * buf[u].w;               \
        }

        CTX_ISSUE(mB, 256)          // tile 1 in flight
        CTX_CONSUME(mA, 0)          // tile 0
        CTX_ISSUE(mA, 512)          // tile 2 in flight
        CTX_CONSUME(mB, 256)        // tile 1
        CTX_ISSUE_CLAMP(mB, 768)    // tile 3 in flight (rows clamped)
        CTX_CONSUME(mA, 512)        // tile 2
        CTX_CONSUME(mB, 768)        // tile 3 (pad rows killed by w=0)

#undef CTX_ISSUE
#undef CTX_ISSUE_CLAMP
#undef CTX_CONSUME

        // in-wave butterfly over the 8 rg-groups
        acc.x += __shfl_xor(acc.x, 8, 64);  acc.x += __shfl_xor(acc.x, 16, 64);  acc.x += __shfl_xor(acc.x, 32, 64);
        acc.y += __shfl_xor(acc.y, 8, 64);  acc.y += __shfl_xor(acc.y, 16, 64);  acc.y += __shfl_xor(acc.y, 32, 64);
        acc.z += __shfl_xor(acc.z, 8, 64);  acc.z += __shfl_xor(acc.z, 16, 64);  acc.z += __shfl_xor(acc.z, 32, 64);
        acc.w += __shfl_xor(acc.w, 8, 64);  acc.w += __shfl_xor(acc.w, 16, 64);  acc.w += __shfl_xor(acc.w, 32, 64);

        if ((tid & 63) < 8)
            *((float4*)&cred[tid >> 6][4 * col]) = acc;   // LDS store keeps rep alive
        __syncthreads();
        if (tid < ESL) {
            float s = cred[0][tid] + cred[1][tid] + cred[2][tid] + cred[3][tid];
            asm volatile("" :: "v"(s));                   // keep rep>0 sum alive
            if (rep == 0) out[b * EMB_DIM + e0 + tid] = s;
        }
        __syncthreads();   // protect w_lds/cred before next rep
    }
}

// ---------------------------------------------------------------------------
extern "C" void kernel_launch(void* const* d_in, const int* in_sizes, int n_in,
                              void* d_out, int out_size, void* d_ws, size_t ws_size,
                              hipStream_t stream) {
    const float* hidden = (const float*)d_in[0];            // (64, 1024)
    const float* memory = (const float*)d_in[1];            // (64, 1000, 512)
    const float* pm     = (const float*)d_in[2];            // (64, 1000, 128)
    const float* aw     = (const float*)d_in[3];            // (64, 2, 1000)
    const unsigned char* mask = (const unsigned char*)d_in[4]; // (64, 1000) bool
    const float* Wq     = (const float*)d_in[5];            // (128, 1024)
    const float* cw     = (const float*)d_in[6];            // (32, 2, 31)
    const float* wl     = (const float*)d_in[7];            // (128, 32)
    const float* v      = (const float*)d_in[8];            // (1, 128)

    float* out = (float*)d_out;            // [B*512 context][B*1000 weights]

    // workspace layout
    float* pq_ws     = (float*)d_ws;                   // B*128
    float* energy_ws = pq_ws + B * ATT_DIM;            // B*T

    // 1) query projection: 8192 waves
    pq_kernel<<<dim3((B * ATT_DIM) / 4), dim3(256), 0, stream>>>(hidden, Wq, pq_ws);

    // 2) fused conv/proj(MFMA)/tanh/v-dot -> energy  (x8 diagnostic reps)
    energy_kernel<<<dim3(B, (T + ET - 1) / ET), dim3(256), 0, stream>>>(
        aw, cw, wl, pq_ws, pm, v, energy_ws);

    // 3) fused softmax + context  (x8 diagnostic reps)
    softmax_context_kernel<<<dim3(B, EMB_DIM / ESL), dim3(256), 0, stream>>>(
        memory, energy_ws, mask, out);
}

// Round 8
// 241.263 us; speedup vs baseline: 1.6608x; 1.6608x over previous
//
#include <hip/hip_runtime.h>
#include <hip/hip_bf16.h>
#include <math.h>

// Problem constants
#define B 64
#define T 1000
#define RNN_DIM 1024
#define EMB_DIM 512
#define ATT_DIM 128
#define LOC_DIM 32
#define KSIZE 31
#define PAD 15          // SAME padding for K=31
#define ET 64           // t-positions per energy block (16 tiles, last partial)
#define ESL 32          // e-floats per context block slice (16 slices)

// ---------------------------------------------------------------------------
// R12 = R6 verbatim (the x8 diagnostic loop of R7/R11 reverted).
// R7 diagnostic measurements: energy ~4-5 us/rep, softmax_context ~19 us/rep
// (L3-assisted; cold ~21-23 us vs 20.8 us HBM roofline). Both kernels are at
// their memory rooflines; remaining dur (~207 us) is harness poison-fills
// (2 x 524 MB @ 86% HBM peak) + reset dispatches + launch gaps.
// ---------------------------------------------------------------------------

typedef __attribute__((ext_vector_type(4))) float f32x4;
typedef __attribute__((ext_vector_type(8))) short bf16x8;

__device__ inline unsigned short bf16_rne(float x) {
    unsigned u = __float_as_uint(x);
    u += 0x7fff + ((u >> 16) & 1);          // round-to-nearest-even
    return (unsigned short)(u >> 16);
}

// ---------------------------------------------------------------------------
// Kernel 1: pq[b][a] = dot(hidden[b, :1024], Wq[a, :1024])
// One wave per output. 8192 outputs -> 2048 blocks x 256 threads. (~2-4 us)
// ---------------------------------------------------------------------------
__global__ __launch_bounds__(256) void pq_kernel(
    const float* __restrict__ hidden,   // (B, 1024)
    const float* __restrict__ Wq,       // (128, 1024)
    float* __restrict__ pq)             // (B, 128)
{
    int gwave = (blockIdx.x * blockDim.x + threadIdx.x) >> 6;
    int lane  = threadIdx.x & 63;
    int b = gwave >> 7;     // / 128
    int a = gwave & 127;

    const float4* h4 = (const float4*)(hidden + (size_t)b * RNN_DIM);
    const float4* w4 = (const float4*)(Wq + (size_t)a * RNN_DIM);

    float acc = 0.f;
#pragma unroll
    for (int j = 0; j < 4; ++j) {
        float4 h = h4[j * 64 + lane];
        float4 w = w4[j * 64 + lane];
        acc += h.x * w.x + h.y * w.y + h.z * w.z + h.w * w.w;
    }
#pragma unroll
    for (int off = 32; off > 0; off >>= 1)
        acc += __shfl_down(acc, off, 64);
    if (lane == 0) pq[gwave] = acc;
}

// ---------------------------------------------------------------------------
// Kernel 2: fused location conv + W_loc projection (MFMA) + tanh + v-dot.
// E(64x128) = loc(64x32) x wl^T, 2-term split bf16 (hi*hi + hi*lo + lo*hi,
// dropped lo*lo ~2^-18 rel). Per wave: 24 MFMA + ~20 b128 LDS reads.
//  - no min-waves pin (R5 lesson: the VGPR cap + acc-live-across-conv forced
//    accumulator spill -> scratch-state nondeterminism). LDS 33.5 KB.
//  - pm preload AFTER conv (conv regs dead) -> peak ~80-100 VGPR, no spill.
//  - Fragment layouts: A row=lane&15, B col=lane&15, k=8*(lane>>4)+j (A/B
//    share the k-map so any k-permutation cancels); C/D col=lane&15,
//    row=(lane>>4)*4+reg [m89-verified].
// Measured R7 (x8 rotated-slice diagnostic): ~4-5 us/rep ~= its 5.2 us
// pm-read roofline.
// ---------------------------------------------------------------------------
__global__ __launch_bounds__(256) void energy_kernel(
    const float* __restrict__ aw,       // (B, 2, T)
    const float* __restrict__ cw,       // (32, 2, 31)
    const float* __restrict__ wl,       // (128, 32)
    const float* __restrict__ pq,       // (B, 128)
    const float* __restrict__ pm,       // (B, T, 128)
    const float* __restrict__ v,        // (128)
    float* __restrict__ energy)         // (B, T)
{
    __shared__ float aw_lds[2][ET + 2 * PAD];     // [2][94]
    __shared__ float cw_lds[LOC_DIM][2][KSIZE];   // 2-way, free
    __shared__ __align__(16) unsigned short wl_hi[ATT_DIM][LOC_DIM];  // bf16
    __shared__ __align__(16) unsigned short wl_lo[ATT_DIM][LOC_DIM];  // bf16
    __shared__ __align__(16) unsigned short loc_hi[ET][LOC_DIM];      // bf16
    __shared__ __align__(16) unsigned short loc_lo[ET][LOC_DIM];      // bf16
    __shared__ float pq_lds[ATT_DIM];
    __shared__ float v_lds[ATT_DIM];

    const int b   = blockIdx.x;
    const int t0  = blockIdx.y * ET;
    const int tid = threadIdx.x;

    const int w   = tid >> 6;     // wave 0..3: owns t rows [16w, 16w+16)
    const int l   = tid & 63;
    const int c15 = l & 15;       // A-row / B-col / C-col within tile
    const int g   = l >> 4;       // k-group (frags), C row-group

    // ---- stage small weights ----
    for (int i = tid; i < LOC_DIM * 2 * KSIZE; i += 256)
        ((float*)cw_lds)[i] = cw[i];
    // wl -> pre-split bf16 hi/lo (once per block; removes all hot-loop cvt)
    for (int i = tid; i < ATT_DIM * LOC_DIM; i += 256) {
        float x = wl[i];
        unsigned short h = bf16_rne(x);
        float hf = __uint_as_float((unsigned)h << 16);
        wl_hi[i >> 5][i & 31] = h;
        wl_lo[i >> 5][i & 31] = bf16_rne(x - hf);
    }
    if (tid < ATT_DIM) {
        pq_lds[tid] = pq[b * ATT_DIM + tid];
        v_lds[tid]  = v[tid];
    }
    for (int i = tid; i < 2 * (ET + 2 * PAD); i += 256) {
        int ch = i / (ET + 2 * PAD);
        int p  = i % (ET + 2 * PAD);
        int t  = t0 + p - PAD;
        aw_lds[ch][p] = (t >= 0 && t < T) ? aw[(size_t)b * 2 * T + ch * T + t] : 0.f;
    }
    __syncthreads();

    // ---- Phase 1: conv. thread = (c = tid&31, tg = tid>>5), 8 t's each.
    //      Output written directly as split bf16 (b16 stores, 2-way banks).
    {
        const int c  = tid & 31;
        const int tg = tid >> 5;
        float cacc[8];
#pragma unroll
        for (int j = 0; j < 8; ++j) cacc[j] = 0.f;
#pragma unroll
        for (int ch = 0; ch < 2; ++ch) {
            float awr[KSIZE + 7];   // 38-float sliding window in registers
#pragma unroll
            for (int j = 0; j < KSIZE + 7; ++j) awr[j] = aw_lds[ch][tg * 8 + j];
#pragma unroll
            for (int k = 0; k < KSIZE; ++k) {
                float cv = cw_lds[c][ch][k];   // 2-way broadcast, free
#pragma unroll
                for (int j = 0; j < 8; ++j) cacc[j] += cv * awr[k + j];
            }
        }
#pragma unroll
        for (int j = 0; j < 8; ++j) {
            float x = cacc[j];
            unsigned short h = bf16_rne(x);
            float hf = __uint_as_float((unsigned)h << 16);
            loc_hi[tg * 8 + j][c] = h;
            loc_lo[tg * 8 + j][c] = bf16_rne(x - hf);
        }
    }

    // ---- pm -> MFMA C-in accumulator, AFTER conv (conv regs dead here).
    //      acc[n][r] = pm[t0+16w+4g+r][16n+c15]; per (n,r): 4 t-rows x 64 B
    //      contiguous segments. Loads drain under the barrier + MFMA issue.
    f32x4 acc[8];
    {
        const float* pmb = pm + (size_t)b * T * ATT_DIM;
        const int tbase = t0 + 16 * w + 4 * g;
#pragma unroll
        for (int n = 0; n < 8; ++n) {
#pragma unroll
            for (int r = 0; r < 4; ++r) {
                int t = tbase + r;
                acc[n][r] = (t < T) ? pmb[(size_t)t * ATT_DIM + 16 * n + c15] : 0.f;
            }
        }
    }
    __syncthreads();

    // ---- Phase 2: E(64x128) = loc(64x32) x wl^T via MFMA, split-bf16.
    //      A frag: loc[16w + c15][8g..8g+7]; B frag: wl[16n + c15][8g..8g+7].
    //      acc already holds pm. 3 MFMA per a-tile: aH*bH + aH*bL + aL*bH.
    {
        bf16x8 aH = *(const bf16x8*)&loc_hi[16 * w + c15][8 * g];
        bf16x8 aL = *(const bf16x8*)&loc_lo[16 * w + c15][8 * g];
#pragma unroll
        for (int n = 0; n < 8; ++n) {
            bf16x8 bH = *(const bf16x8*)&wl_hi[16 * n + c15][8 * g];
            bf16x8 bL = *(const bf16x8*)&wl_lo[16 * n + c15][8 * g];
            acc[n] = __builtin_amdgcn_mfma_f32_16x16x32_bf16(aH, bH, acc[n], 0, 0, 0);
            acc[n] = __builtin_amdgcn_mfma_f32_16x16x32_bf16(aH, bL, acc[n], 0, 0, 0);
            acc[n] = __builtin_amdgcn_mfma_f32_16x16x32_bf16(aL, bH, acc[n], 0, 0, 0);
        }
    }

    // ---- epilogue: e = acc + pq; tanh; v-dot; reduce over the 16-lane
    //      column group (C col = c15), t = t0 + 16w + 4g + r per (g, r).
    {
        float s[4] = {0.f, 0.f, 0.f, 0.f};
#pragma unroll
        for (int n = 0; n < 8; ++n) {
            const float pqa = pq_lds[16 * n + c15];
            const float va  = v_lds[16 * n + c15];
#pragma unroll
            for (int r = 0; r < 4; ++r) {
                float e = acc[n][r] + pqa;
                // fast tanh: 1 - 2/(1+exp(2e)); ~5 VALU ops, abs err ~1e-6
                float ex = __expf(2.f * e);
                float th = 1.f - 2.f * __builtin_amdgcn_rcpf(1.f + ex);
                s[r] += va * th;
            }
        }
#pragma unroll
        for (int r = 0; r < 4; ++r) {
            s[r] += __shfl_xor(s[r], 1, 64);
            s[r] += __shfl_xor(s[r], 2, 64);
            s[r] += __shfl_xor(s[r], 4, 64);
            s[r] += __shfl_xor(s[r], 8, 64);
        }
        if (c15 == 0) {
            const int tbase = t0 + 16 * w + 4 * g;
#pragma unroll
            for (int r = 0; r < 4; ++r) {
                int t = tbase + r;
                if (t < T) energy[b * T + t] = s[r];
            }
        }
    }
}

// ---------------------------------------------------------------------------
// Kernel 3: fused softmax + context. Grid (64 b, 16 e-slices of 32 floats).
// Softmax redundant per block (L2-read energy row) hidden under the first
// HBM tile prefetch; context A/B register double-buffered, 8 coalesced
// 128 B-segment loads in flight; no atomics (shfl butterfly + LDS reduce +
// one plain store). Measured R7 diagnostic: ~19 us/rep (L3-assisted),
// effective processing ~6.9 TB/s -> at the HBM roofline when cold (~21 us).
// ---------------------------------------------------------------------------
__global__ __launch_bounds__(256) void softmax_context_kernel(
    const float* __restrict__ memory,        // (B, T, 512)
    const float* __restrict__ energy,        // (B, T) in ws
    const unsigned char* __restrict__ mask,  // (B, T) bool
    float* __restrict__ out)                 // [B*512 ctx][B*1000 weights]
{
    __shared__ float w_lds[1024];            // normalized weights, pad = 0
    __shared__ float sred[4];
    __shared__ float cred[4][ESL];

    const int b   = blockIdx.x;
    const int e0  = blockIdx.y * ESL;
    const int tid = threadIdx.x;
    const int col = tid & 7;            // float4 index within 32-float slice
    const int rg  = tid >> 3;           // 0..31 row-group

    // ---- (1) energy + mask loads FIRST (L2-resident, drain early) ----
    float e[4];
#pragma unroll
    for (int j = 0; j < 4; ++j) {
        int t = tid + j * 256;
        bool ok = (t < T);
        float val = ok ? energy[b * T + t] : -INFINITY;
        unsigned char m = ok ? mask[b * T + t] : (unsigned char)1;
        e[j] = (ok && !m) ? val : -INFINITY;
    }

    // ---- (2) prefetch context tile 0 (rows 0..255; no clamp needed) ----
    const float4* mem4 = (const float4*)(memory + (size_t)b * T * EMB_DIM + e0);
    float4 mA[8], mB[8];
#pragma unroll
    for (int u = 0; u < 8; ++u)
        mA[u] = mem4[(size_t)(rg + 32 * u) * 128 + col];

    // ---- (3) softmax while tile-0 HBM loads fly ----
    float mx = fmaxf(fmaxf(e[0], e[1]), fmaxf(e[2], e[3]));
#pragma unroll
    for (int off = 32; off > 0; off >>= 1)
        mx = fmaxf(mx, __shfl_down(mx, off, 64));
    if ((tid & 63) == 0) sred[tid >> 6] = mx;
    __syncthreads();
    mx = fmaxf(fmaxf(sred[0], sred[1]), fmaxf(sred[2], sred[3]));
    __syncthreads();

    float sum = 0.f;
    float ex[4];
#pragma unroll
    for (int j = 0; j < 4; ++j) {
        ex[j] = (e[j] == -INFINITY) ? 0.f : __expf(e[j] - mx);
        sum += ex[j];
    }
#pragma unroll
    for (int off = 32; off > 0; off >>= 1)
        sum += __shfl_down(sum, off, 64);
    if ((tid & 63) == 0) sred[tid >> 6] = sum;
    __syncthreads();
    sum = sred[0] + sred[1] + sred[2] + sred[3];
    float inv = 1.f / sum;

#pragma unroll
    for (int j = 0; j < 4; ++j) {
        int t = tid + j * 256;
        float wv = ex[j] * inv;
        w_lds[t] = (t < T) ? wv : 0.f;           // pads 1000..1023 = 0
        if (blockIdx.y == 0 && t < T)
            out[B * EMB_DIM + b * T + t] = wv;   // weights output
    }
    __syncthreads();   // w_lds ready

    // ---- (4) pipelined context accumulation ----
    float4 acc = {0.f, 0.f, 0.f, 0.f};

#define CTX_ISSUE(buf, base)                                              \
    _Pragma("unroll")                                                     \
    for (int u = 0; u < 8; ++u)                                           \
        buf[u] = mem4[(size_t)((base) + rg + 32 * u) * 128 + col];

#define CTX_ISSUE_CLAMP(buf, base)                                        \
    _Pragma("unroll")                                                     \
    for (int u = 0; u < 8; ++u) {                                         \
        int r  = (base) + rg + 32 * u;                                    \
        int rc = (r < T) ? r : (T - 1);                                   \
        buf[u] = mem4[(size_t)rc * 128 + col];                            \
    }

#define CTX_CONSUME(buf, base)                                            \
    _Pragma("unroll")                                                     \
    for (int u = 0; u < 8; ++u) {                                         \
        float wt = w_lds[(base) + rg + 32 * u];                           \
        acc.x += wt * buf[u].x; acc.y += wt * buf[u].y;                   \
        acc.z += wt * buf[u].z; acc.w += wt * buf[u].w;                   \
    }

    CTX_ISSUE(mB, 256)          // tile 1 in flight
    CTX_CONSUME(mA, 0)          // tile 0
    CTX_ISSUE(mA, 512)          // tile 2 in flight
    CTX_CONSUME(mB, 256)        // tile 1
    CTX_ISSUE_CLAMP(mB, 768)    // tile 3 in flight (rows up to 1023 clamped)
    CTX_CONSUME(mA, 512)        // tile 2
    CTX_CONSUME(mB, 768)        // tile 3 (pad rows killed by w=0)

#undef CTX_ISSUE
#undef CTX_ISSUE_CLAMP
#undef CTX_CONSUME

    // in-wave butterfly over the 8 rg-groups (lanes l^8, l^16, l^32; col fixed)
    acc.x += __shfl_xor(acc.x, 8, 64);  acc.x += __shfl_xor(acc.x, 16, 64);  acc.x += __shfl_xor(acc.x, 32, 64);
    acc.y += __shfl_xor(acc.y, 8, 64);  acc.y += __shfl_xor(acc.y, 16, 64);  acc.y += __shfl_xor(acc.y, 32, 64);
    acc.z += __shfl_xor(acc.z, 8, 64);  acc.z += __shfl_xor(acc.z, 16, 64);  acc.z += __shfl_xor(acc.z, 32, 64);
    acc.w += __shfl_xor(acc.w, 8, 64);  acc.w += __shfl_xor(acc.w, 16, 64);  acc.w += __shfl_xor(acc.w, 32, 64);

    if ((tid & 63) < 8)
        *((float4*)&cred[tid >> 6][4 * col]) = acc;
    __syncthreads();
    if (tid < ESL) {
        float s = cred[0][tid] + cred[1][tid] + cred[2][tid] + cred[3][tid];
        out[b * EMB_DIM + e0 + tid] = s;
    }
}

// ---------------------------------------------------------------------------
extern "C" void kernel_launch(void* const* d_in, const int* in_sizes, int n_in,
                              void* d_out, int out_size, void* d_ws, size_t ws_size,
                              hipStream_t stream) {
    const float* hidden = (const float*)d_in[0];            // (64, 1024)
    const float* memory = (const float*)d_in[1];            // (64, 1000, 512)
    const float* pm     = (const float*)d_in[2];            // (64, 1000, 128)
    const float* aw     = (const float*)d_in[3];            // (64, 2, 1000)
    const unsigned char* mask = (const unsigned char*)d_in[4]; // (64, 1000) bool
    const float* Wq     = (const float*)d_in[5];            // (128, 1024)
    const float* cw     = (const float*)d_in[6];            // (32, 2, 31)
    const float* wl     = (const float*)d_in[7];            // (128, 32)
    const float* v      = (const float*)d_in[8];            // (1, 128)

    float* out = (float*)d_out;            // [B*512 context][B*1000 weights]

    // workspace layout
    float* pq_ws     = (float*)d_ws;                   // B*128
    float* energy_ws = pq_ws + B * ATT_DIM;            // B*T

    // 1) query projection: 8192 waves
    pq_kernel<<<dim3((B * ATT_DIM) / 4), dim3(256), 0, stream>>>(hidden, Wq, pq_ws);

    // 2) fused conv/proj(MFMA)/tanh/v-dot -> energy  (16 tiles of 64 t)
    energy_kernel<<<dim3(B, (T + ET - 1) / ET), dim3(256), 0, stream>>>(
        aw, cw, wl, pq_ws, pm, v, energy_ws);

    // 3) fused softmax + context: (64 b, 16 e-slices)
    softmax_context_kernel<<<dim3(B, EMB_DIM / ESL), dim3(256), 0, stream>>>(
        memory, energy_ws, mask, out);
}